// Round 11
// baseline (200.518 us; speedup 1.0000x reference)
//
#include <hip/hip_runtime.h>
#include <math.h>

#define NB 4096
#define NIN 128
#define NH 256
#define ND 32
#define NC 8
#define NK 256
#define NHS 16

// output offsets (in floats), concatenated in reference return order
#define OFF_KCHART 0
#define OFF_KCODE  4096
#define OFF_ZN     8192
#define OFF_ZTEX   (OFF_ZN + 4096*32)        // 139264
#define OFF_ROUTER (OFF_ZTEX + 4096*32)      // 270336 (float4-aligned)
#define OFF_ZGEO   (OFF_ROUTER + 4096*8)     // 303104
#define OFF_LOSS   (OFF_ZGEO + 4096*32)      // 434176
#define OFF_IND    (OFF_LOSS + 1)            // 434177 (odd -> scalar access only)
#define OFF_ZNALL  (OFF_IND + 4096*8)        // 466945 (odd -> scalar access only)
#define OFF_CBAR   (OFF_ZNALL + 4096*8*32)   // 1515521 (odd -> scalar)
#define OFF_VLOC   (OFF_CBAR + 4096*32)      // 1646593 (odd -> scalar)

__device__ __forceinline__ float gelu_exact(float x) {
    return x * (erff(x / 1.41421356237309504f) + 1.0f) * 0.5f;
}

// Manual grid barrier: monotonic counter, reset each launch by hipMemsetAsync.
// 512 blocks are ALL co-resident (launch_bounds(256,2) + 55.4KB LDS -> 2/CU
// x 256 CU = 512), so spinning cannot starve. Release fence before arrive,
// agent-scope acquire spin after (the same lowering AMD grid.sync uses).
__device__ __forceinline__ void gbar(int* bar, int target) {
    __syncthreads();
    if (threadIdx.x == 0) {
        __threadfence();   // device-scope release of all prior writes
        __hip_atomic_fetch_add(bar, 1, __ATOMIC_ACQ_REL, __HIP_MEMORY_SCOPE_AGENT);
        while (__hip_atomic_load(bar, __ATOMIC_ACQUIRE, __HIP_MEMORY_SCOPE_AGENT) < target) {
            __builtin_amdgcn_s_sleep(1);
        }
    }
    __syncthreads();
}

struct SmemGemm   { float sB[2][32][68]; };                          // 17.4 KB
struct SmemRouter { float sWv[32 * 272]; float sCent[NC * ND];
                    float sV[8][ND + 2]; float sScore[8][NC];
                    float sRout[8][NC]; };                           // 35.6 KB
struct SmemVq     { float sCB[NK][36]; float sEn2[NK]; float sV[64][36];
                    float sBest[8][64]; int sBidx[8][64]; int sSel[64];
                    float sRoutv[64]; float sPscale[64]; float sLossArr[64];
                    float sWs1[ND][17]; float sWs2[NHS][33];
                    float sbs1[NHS]; float sbs2v[ND]; };             // 55.4 KB
union SmemAll { SmemGemm g; SmemRouter r; SmemVq v; float sTmp[4]; };

// ---------------------------------------------------------------------------
// Phase 1/2: gemm (r6-verified): 32x64 tile, 2x4 micro, 512 blocks.
// ---------------------------------------------------------------------------
template<int K>
__device__ __forceinline__
void gemm_phase(const float* __restrict__ A, const float* __restrict__ W,
                const float* __restrict__ bias, float* __restrict__ outp,
                SmemGemm& sm, int b, int t) {
    const int N = 256;
    const int n0 = (b & 3) * 64;
    const int r0 = (b >> 2) * 32;
    const int ty = t >> 4, tx = t & 15;
    const int bk = t >> 4, bc = t & 15;

    float4 bias4 = *(const float4*)(bias + n0 + tx * 4);

    float4 pb0 = *(const float4*)(W + bk * N + n0 + bc * 4);
    float4 pb1 = *(const float4*)(W + (bk + 16) * N + n0 + bc * 4);

    const float* Ab0 = A + (r0 + ty * 2 + 0) * K;
    const float* Ab1 = A + (r0 + ty * 2 + 1) * K;
    float ac[2][4], an[2][4];
    {
        float4 c0 = *(const float4*)(Ab0 + 0), c1 = *(const float4*)(Ab1 + 0);
        ac[0][0]=c0.x; ac[0][1]=c0.y; ac[0][2]=c0.z; ac[0][3]=c0.w;
        ac[1][0]=c1.x; ac[1][1]=c1.y; ac[1][2]=c1.z; ac[1][3]=c1.w;
        float4 d0 = *(const float4*)(Ab0 + 4), d1 = *(const float4*)(Ab1 + 4);
        an[0][0]=d0.x; an[0][1]=d0.y; an[0][2]=d0.z; an[0][3]=d0.w;
        an[1][0]=d1.x; an[1][1]=d1.y; an[1][2]=d1.z; an[1][3]=d1.w;
    }

    float acc[2][4];
    #pragma unroll
    for (int i = 0; i < 2; i++)
        #pragma unroll
        for (int j = 0; j < 4; j++) acc[i][j] = 0.f;

    int buf = 0;
    for (int kk = 0; kk < K; kk += 32) {
        *(float4*)(&sm.sB[buf][bk][bc*4])    = pb0;
        *(float4*)(&sm.sB[buf][bk+16][bc*4]) = pb1;
        __syncthreads();
        if (kk + 32 < K) {
            pb0 = *(const float4*)(W + (kk + 32 + bk) * N + n0 + bc * 4);
            pb1 = *(const float4*)(W + (kk + 32 + bk + 16) * N + n0 + bc * 4);
        }
        #pragma unroll
        for (int c = 0; c < 8; c++) {
            int knext = kk + (c + 2) * 4;
            if (knext > K - 4) knext = K - 4;
            float4 p0 = *(const float4*)(Ab0 + knext);
            float4 p1 = *(const float4*)(Ab1 + knext);
            #pragma unroll
            for (int u = 0; u < 4; u++) {
                float4 bv = *(const float4*)(&sm.sB[buf][c * 4 + u][tx * 4]);
                float bb[4] = {bv.x, bv.y, bv.z, bv.w};
                #pragma unroll
                for (int j = 0; j < 4; j++) {
                    acc[0][j] = fmaf(ac[0][u], bb[j], acc[0][j]);
                    acc[1][j] = fmaf(ac[1][u], bb[j], acc[1][j]);
                }
            }
            #pragma unroll
            for (int u = 0; u < 4; u++) { ac[0][u] = an[0][u]; ac[1][u] = an[1][u]; }
            an[0][0]=p0.x; an[0][1]=p0.y; an[0][2]=p0.z; an[0][3]=p0.w;
            an[1][0]=p1.x; an[1][1]=p1.y; an[1][2]=p1.z; an[1][3]=p1.w;
        }
        buf ^= 1;
    }
    float bb4[4] = {bias4.x, bias4.y, bias4.z, bias4.w};
    #pragma unroll
    for (int i = 0; i < 2; i++) {
        int row = r0 + ty * 2 + i;
        float4 o;
        float* op = (float*)&o;
        #pragma unroll
        for (int j = 0; j < 4; j++) op[j] = gelu_exact(acc[i][j] + bb4[j]);
        *(float4*)(outp + row * N + n0 + tx * 4) = o;
    }
}

// ---------------------------------------------------------------------------
// Phase 3: router (r9-verified): 8 rows/block, one col/thread, swizzled Wv.
// ---------------------------------------------------------------------------
__device__ __forceinline__
void router_phase(const float* __restrict__ feats, const float* __restrict__ Wv,
                  const float* __restrict__ bv, const float* __restrict__ centers,
                  float* __restrict__ out, float* __restrict__ vloc_ws,
                  SmemRouter& sm, int b, int t) {
    const int row0 = b * 8;
    {
        #pragma unroll
        for (int q = 0; q < 8; q++) {
            int id = t + q * 256;
            int k = id >> 3, c4 = (id & 7) * 4;
            int kb = k >> 2, kr = k & 3;
            float4 w = ((const float4*)Wv)[id];
            sm.sWv[(c4+0) * 272 + ((kb ^ ((c4+0) & 7)) << 2) + kr] = w.x;
            sm.sWv[(c4+1) * 272 + ((kb ^ ((c4+1) & 7)) << 2) + kr] = w.y;
            sm.sWv[(c4+2) * 272 + ((kb ^ ((c4+2) & 7)) << 2) + kr] = w.z;
            sm.sWv[(c4+3) * 272 + ((kb ^ ((c4+3) & 7)) << 2) + kr] = w.w;
        }
        if (t < 64) ((float4*)sm.sCent)[t] = ((const float4*)centers)[t];
    }
    __syncthreads();
    const int r = t >> 5, cp = t & 31;
    const int row = row0 + r;
    const int cbase = cp * 272, cxor = cp & 7;
    float a0 = bv[cp];
    const float4* f4 = (const float4*)(feats + row * NH);
    for (int k4 = 0; k4 < NH / 4; k4++) {
        float4 f = f4[k4];
        float4 w = *(const float4*)(&sm.sWv[cbase + ((k4 ^ cxor) << 2)]);
        a0 = fmaf(f.x, w.x, a0);
        a0 = fmaf(f.y, w.y, a0);
        a0 = fmaf(f.z, w.z, a0);
        a0 = fmaf(f.w, w.w, a0);
    }
    sm.sV[r][cp] = a0;
    __syncthreads();
    if (t < 64) {
        int rr = t >> 3, c = t & 7;
        float s = 0.f;
        #pragma unroll
        for (int k = 0; k < ND; k++) s = fmaf(sm.sV[rr][k], sm.sCent[c * ND + k], s);
        sm.sScore[rr][c] = s / 5.65685424949238f;
    }
    __syncthreads();
    if (t < 8) {
        const int rr = t, grow = row0 + rr;
        float sc[NC];
        float m = -3.4e38f; int kmax = 0;
        #pragma unroll
        for (int c = 0; c < NC; c++) {
            float s = sm.sScore[rr][c];
            sc[c] = s;
            if (s > m) { m = s; kmax = c; }
        }
        float ssum = 0.f;
        #pragma unroll
        for (int c = 0; c < NC; c++) { float e = expf(sc[c] - m); sc[c] = e; ssum += e; }
        float inv = 1.f / ssum;
        #pragma unroll
        for (int c = 0; c < NC; c++) {
            float rv = sc[c] * inv;
            sm.sRout[rr][c] = rv;
            out[OFF_ROUTER + grow * NC + c] = rv;
        }
        out[OFF_KCHART + grow] = (float)kmax;
    }
    __syncthreads();
    {
        const int col = cp;
        float cb = 0.f;
        #pragma unroll
        for (int c = 0; c < NC; c++) cb = fmaf(sm.sRout[r][c], sm.sCent[c * ND + col], cb);
        float vl = sm.sV[r][col] - cb;
        out[OFF_CBAR + row * ND + col] = cb;
        out[OFF_VLOC + row * ND + col] = vl;
        vloc_ws[row * ND + col] = vl;
    }
}

// ---------------------------------------------------------------------------
// Phase 4: vq (r6-verified): 64 rows x 1 chart, 2-row argmin, En2 hoisted.
// ---------------------------------------------------------------------------
__device__ __forceinline__
void vq_phase(const float* __restrict__ codebook, const float* __restrict__ vloc_ws,
              const float* __restrict__ Ws1, const float* __restrict__ bs1,
              const float* __restrict__ Ws2, const float* __restrict__ bs2,
              float* __restrict__ out, float* __restrict__ loss_partial,
              SmemVq& sm, int b, int t) {
    const int c = b & 7;
    const int row0 = (b >> 3) * 64;

    {
        const float4* src = (const float4*)(codebook + c * NK * ND);
        #pragma unroll
        for (int q = 0; q < 8; q++) {
            int id = t + q * 256;
            int code = id >> 3, kq = (id & 7) * 4;
            *(float4*)(&sm.sCB[code][kq]) = src[id];
        }
        #pragma unroll
        for (int q = 0; q < 2; q++) {
            int id = t + q * 256;
            int rr = id >> 3, kq = (id & 7) * 4;
            *(float4*)(&sm.sV[rr][kq]) = ((const float4*)(vloc_ws + row0 * ND))[id];
        }
    }
    if (t < 128) {
        float4 w = ((const float4*)Ws1)[t];
        int k = t >> 2, o = (t & 3) * 4;
        sm.sWs1[k][o] = w.x; sm.sWs1[k][o+1] = w.y;
        sm.sWs1[k][o+2] = w.z; sm.sWs1[k][o+3] = w.w;
    } else {
        int u = t - 128;
        float4 w = ((const float4*)Ws2)[u];
        int k = u >> 3, o = (u & 7) * 4;
        sm.sWs2[k][o] = w.x; sm.sWs2[k][o+1] = w.y;
        sm.sWs2[k][o+2] = w.z; sm.sWs2[k][o+3] = w.w;
    }
    if (t < NHS) sm.sbs1[t] = bs1[t];
    else if (t < NHS + ND) sm.sbs2v[t - NHS] = bs2[t - NHS];
    if (t < 64) sm.sRoutv[t] = out[OFF_ROUTER + (row0 + t) * NC + c];
    __syncthreads();
    {
        float s = 0.f;
        #pragma unroll
        for (int q = 0; q < 8; q++) {
            float4 e = *(const float4*)(&sm.sCB[t][q * 4]);
            s = fmaf(e.x, e.x, s); s = fmaf(e.y, e.y, s);
            s = fmaf(e.z, e.z, s); s = fmaf(e.w, e.w, s);
        }
        sm.sEn2[t] = s;
    }
    __syncthreads();

    const int r = t & 31, g = t >> 5;
    float vl0[ND], vl1[ND];
    #pragma unroll
    for (int q = 0; q < 8; q++) {
        float4 a = *(const float4*)(&sm.sV[r][q * 4]);
        vl0[q*4] = a.x; vl0[q*4+1] = a.y; vl0[q*4+2] = a.z; vl0[q*4+3] = a.w;
        float4 bb = *(const float4*)(&sm.sV[r + 32][q * 4]);
        vl1[q*4] = bb.x; vl1[q*4+1] = bb.y; vl1[q*4+2] = bb.z; vl1[q*4+3] = bb.w;
    }
    float best0 = 3.4e38f, best1 = 3.4e38f;
    int bi0 = 0, bi1 = 0;
    for (int j = 0; j < 32; j++) {
        const int code = g * 32 + j;
        float dot0 = 0.f, dot1 = 0.f;
        #pragma unroll
        for (int q = 0; q < 8; q++) {
            float4 e = *(const float4*)(&sm.sCB[code][q * 4]);
            dot0 = fmaf(vl0[q*4+0], e.x, dot0); dot1 = fmaf(vl1[q*4+0], e.x, dot1);
            dot0 = fmaf(vl0[q*4+1], e.y, dot0); dot1 = fmaf(vl1[q*4+1], e.y, dot1);
            dot0 = fmaf(vl0[q*4+2], e.z, dot0); dot1 = fmaf(vl1[q*4+2], e.z, dot1);
            dot0 = fmaf(vl0[q*4+3], e.w, dot0); dot1 = fmaf(vl1[q*4+3], e.w, dot1);
        }
        const float en2 = sm.sEn2[code];
        float d0 = en2 - 2.f * dot0;
        float d1 = en2 - 2.f * dot1;
        if (d0 < best0) { best0 = d0; bi0 = code; }
        if (d1 < best1) { best1 = d1; bi1 = code; }
    }
    sm.sBest[g][r] = best0;      sm.sBidx[g][r] = bi0;
    sm.sBest[g][r + 32] = best1; sm.sBidx[g][r + 32] = bi1;
    __syncthreads();
    if (t < 64) {
        float bb = sm.sBest[0][t]; int ii = sm.sBidx[0][t];
        #pragma unroll
        for (int gg = 1; gg < 8; gg++) {
            float v = sm.sBest[gg][t];
            if (v < bb) { bb = v; ii = sm.sBidx[gg][t]; }
        }
        sm.sSel[t] = ii;
        out[OFF_IND + (row0 + t) * NC + c] = (float)ii;
        float vn2 = 0.f;
        #pragma unroll
        for (int k = 0; k < ND; k++) { float v = sm.sV[t][k]; vn2 = fmaf(v, v, vn2); }
        float norm = fmaxf(sqrtf(vn2), 1e-6f);
        sm.sPscale[t] = fminf(0.99f / norm, 1.0f);
    }
    __syncthreads();

    const int i = t & 15, r16 = t >> 4;
    const float b1r = sm.sbs1[i];
    const float bo0 = sm.sbs2v[2*i], bo1 = sm.sbs2v[2*i+1];
    #pragma unroll
    for (int pass = 0; pass < 4; pass++) {
        const int lrow = pass * 16 + r16;
        const int grow = row0 + lrow;
        const int sel = sm.sSel[lrow];
        const float rc = sm.sRoutv[lrow];
        const float ps = sm.sPscale[lrow];
        float acc1 = b1r;
        #pragma unroll
        for (int k = 0; k < ND; k++) {
            float dlt = sm.sV[lrow][k] - sm.sCB[sel][k];
            acc1 = fmaf(dlt, sm.sWs1[k][i], acc1);
        }
        float h = gelu_exact(acc1);
        float a0 = bo0, a1 = bo1;
        #pragma unroll
        for (int k = 0; k < NHS; k++) {
            float s1k = __shfl(h, k, 16);
            a0 = fmaf(s1k, sm.sWs2[k][2*i],   a0);
            a1 = fmaf(s1k, sm.sWs2[k][2*i+1], a1);
        }
        out[OFF_ZNALL + (grow * NC + c) * ND + 2*i]     = a0;
        out[OFF_ZNALL + (grow * NC + c) * ND + 2*i + 1] = a1;
        const float e0 = sm.sCB[sel][2*i], e1 = sm.sCB[sel][2*i+1];
        float yp0 = sm.sV[lrow][2*i] * ps, yp1 = sm.sV[lrow][2*i+1] * ps;
        float d0 = e0 - yp0, d1 = e1 - yp1;
        float sq = fmaf(d0, d0, d1 * d1);
        float xn = fmaf(e0, e0, e1 * e1);
        float yn = fmaf(yp0, yp0, yp1 * yp1);
        #pragma unroll
        for (int m = 1; m < 16; m <<= 1) {
            sq += __shfl_xor(sq, m, 16);
            xn += __shfl_xor(xn, m, 16);
            yn += __shfl_xor(yn, m, 16);
        }
        if (i == 0) {
            float denom = fmaxf((1.f - xn) * (1.f - yn), 1e-6f);
            float arg = fmaxf(1.f + 2.f * sq / denom, 1.f + 1e-6f);
            float dd = acoshf(arg);
            sm.sLossArr[lrow] = dd * dd * rc;
        }
    }
    __syncthreads();
    if (t < 64) {
        float v = sm.sLossArr[t];
        #pragma unroll
        for (int off = 32; off > 0; off >>= 1) v += __shfl_down(v, off, 64);
        if (t == 0) loss_partial[b] = v;
    }
}

// ---------------------------------------------------------------------------
// Phase 5: finalize (r9-verified): one col/thread + loss reduce in block 0.
// ---------------------------------------------------------------------------
__device__ __forceinline__
void finalize_phase(const float* __restrict__ codebook, const float* __restrict__ vloc_ws,
                    float* __restrict__ out, const float* __restrict__ partials,
                    float* sTmp, int b, int t) {
    const int gid = b * 256 + t;
    const int row = gid >> 5;
    const int col = gid & 31;
    float rout[NC]; int ind[NC];
    #pragma unroll
    for (int cc = 0; cc < NC; cc++) {
        rout[cc] = out[OFF_ROUTER + row * NC + cc];
        ind[cc]  = (int)out[OFF_IND + row * NC + cc];
    }
    float zn = 0.f, zq = 0.f;
    #pragma unroll
    for (int cc = 0; cc < NC; cc++) {
        const float rcc = rout[cc];
        zn = fmaf(out[OFF_ZNALL + (row * NC + cc) * ND + col], rcc, zn);
        zq = fmaf(codebook[(cc * NK + ind[cc]) * ND + col], rcc, zq);
    }
    const float vl = vloc_ws[row * ND + col];
    const float cb = out[OFF_CBAR + row * ND + col];
    out[OFF_ZN   + row * ND + col] = zn;
    out[OFF_ZTEX + row * ND + col] = vl - zq - zn;
    out[OFF_ZGEO + row * ND + col] = cb + zq + zn;
    if (col == 0) {
        int kc = (int)out[OFF_KCHART + row];
        out[OFF_KCODE + row] = out[OFF_IND + row * NC + kc];
    }
    if (b == 0) {
        float v = partials[t] + partials[t + 256];
        #pragma unroll
        for (int off = 32; off > 0; off >>= 1) v += __shfl_down(v, off, 64);
        if ((t & 63) == 0) sTmp[t >> 6] = v;
        __syncthreads();
        if (t == 0) out[OFF_LOSS] = 1.25f * (sTmp[0] + sTmp[1] + sTmp[2] + sTmp[3]) / 4096.f;
    }
}

// ---------------------------------------------------------------------------
// Persistent mega-kernel: 512 blocks x 256 threads, 5 phases, 4 atomic
// grid barriers. LDS union 55.4 KB + launch_bounds(256,2) -> exactly
// 2 blocks/CU -> all 512 blocks co-resident (barrier cannot starve).
// ---------------------------------------------------------------------------
__global__ __launch_bounds__(256, 2)
void atlas_fused(const float* __restrict__ x, const float* __restrict__ W1,
                 const float* __restrict__ b1, const float* __restrict__ W2,
                 const float* __restrict__ b2, const float* __restrict__ Wv,
                 const float* __restrict__ bv, const float* __restrict__ centers,
                 const float* __restrict__ codebook, const float* __restrict__ Ws1,
                 const float* __restrict__ bs1, const float* __restrict__ Ws2,
                 const float* __restrict__ bs2, float* __restrict__ out,
                 float* __restrict__ h1, float* __restrict__ feats,
                 float* __restrict__ vloc, float* __restrict__ partials,
                 int* __restrict__ bar) {
    __shared__ SmemAll sm;
    const int t = threadIdx.x;
    const int b = blockIdx.x;

    gemm_phase<128>(x, W1, b1, h1, sm.g, b, t);
    gbar(bar, 512);
    gemm_phase<256>(h1, W2, b2, feats, sm.g, b, t);
    gbar(bar, 1024);
    router_phase(feats, Wv, bv, centers, out, vloc, sm.r, b, t);
    gbar(bar, 1536);
    vq_phase(codebook, vloc, Ws1, bs1, Ws2, bs2, out, partials, sm.v, b, t);
    gbar(bar, 2048);
    finalize_phase(codebook, vloc, out, partials, sm.sTmp, b, t);
}

extern "C" void kernel_launch(void* const* d_in, const int* in_sizes, int n_in,
                              void* d_out, int out_size, void* d_ws, size_t ws_size,
                              hipStream_t stream) {
    const float* x        = (const float*)d_in[0];
    const float* W1       = (const float*)d_in[1];
    const float* b1       = (const float*)d_in[2];
    const float* W2       = (const float*)d_in[3];
    const float* b2       = (const float*)d_in[4];
    const float* Wv       = (const float*)d_in[5];
    const float* bv       = (const float*)d_in[6];
    const float* centers  = (const float*)d_in[7];
    const float* codebook = (const float*)d_in[8];
    const float* Ws1      = (const float*)d_in[9];
    const float* bs1      = (const float*)d_in[10];
    const float* Ws2      = (const float*)d_in[11];
    const float* bs2      = (const float*)d_in[12];
    float* out = (float*)d_out;
    float* ws  = (float*)d_ws;

    float* h1       = ws;                                // 4096*256
    float* feats    = ws + 4096 * 256;                   // 4096*256
    float* vloc     = ws + 2 * 4096 * 256;               // 4096*32
    float* partials = ws + 2 * 4096 * 256 + 4096 * 32;   // 512
    int*   bar      = (int*)(ws + 2 * 4096 * 256 + 4096 * 32 + 1024);

    hipMemsetAsync(bar, 0, 128, stream);   // reset barrier counter each launch
    atlas_fused<<<dim3(512), dim3(256), 0, stream>>>(
        x, W1, b1, W2, b2, Wv, bv, centers, codebook,
        Ws1, bs1, Ws2, bs2, out, h1, feats, vloc, partials, bar);
}

// Round 12
// 124.189 us; speedup vs baseline: 1.6146x; 1.6146x over previous
//
#include <hip/hip_runtime.h>
#include <math.h>

#define NB 4096
#define NIN 128
#define NH 256
#define ND 32
#define NC 8
#define NK 256
#define NHS 16

// output offsets (in floats), concatenated in reference return order
#define OFF_KCHART 0
#define OFF_KCODE  4096
#define OFF_ZN     8192
#define OFF_ZTEX   (OFF_ZN + 4096*32)        // 139264
#define OFF_ROUTER (OFF_ZTEX + 4096*32)      // 270336 (float4-aligned)
#define OFF_ZGEO   (OFF_ROUTER + 4096*8)     // 303104
#define OFF_LOSS   (OFF_ZGEO + 4096*32)      // 434176
#define OFF_IND    (OFF_LOSS + 1)            // 434177 (odd -> scalar access only)
#define OFF_ZNALL  (OFF_IND + 4096*8)        // 466945 (odd -> scalar access only)
#define OFF_CBAR   (OFF_ZNALL + 4096*8*32)   // 1515521 (odd -> scalar)
#define OFF_VLOC   (OFF_CBAR + 4096*32)      // 1646593 (odd -> scalar)

__device__ __forceinline__ float gelu_exact(float x) {
    return x * (erff(x / 1.41421356237309504f) + 1.0f) * 0.5f;
}

// ---------------------------------------------------------------------------
// GEMM v4 "stream": out = gelu(A[M][K] @ W[K][256] + b). 32x64 tile, 2x4
// micro, grid (4,128)=512. NO LDS, NO barriers: A and B both streamed from
// global (B slice is L2-resident, shared by 64 row-blocks; per-wave B reads
// coalesce to 16x16B). 8-k register chunks, unroll-2 ping-pong prefetch
// (64 FMA/chunk x 2 waves/SIMD = 256 cy >= L2 latency). FMA order identical
// to r6/r9 (k ascending, j inner, rows interleaved) -> bit-identical output.
// ---------------------------------------------------------------------------
#define GEMM_COMPUTE(AR0, AR1, BV)                                  \
    {                                                               \
        float ar0[8] = {AR0##a.x, AR0##a.y, AR0##a.z, AR0##a.w,     \
                        AR0##b.x, AR0##b.y, AR0##b.z, AR0##b.w};    \
        float ar1[8] = {AR1##a.x, AR1##a.y, AR1##a.z, AR1##a.w,     \
                        AR1##b.x, AR1##b.y, AR1##b.z, AR1##b.w};    \
        _Pragma("unroll")                                           \
        for (int u = 0; u < 8; u++) {                               \
            float bb[4] = {BV[u].x, BV[u].y, BV[u].z, BV[u].w};     \
            _Pragma("unroll")                                       \
            for (int j = 0; j < 4; j++) {                           \
                acc[0][j] = fmaf(ar0[u], bb[j], acc[0][j]);         \
                acc[1][j] = fmaf(ar1[u], bb[j], acc[1][j]);         \
            }                                                       \
        }                                                           \
    }

template<int K>
__global__ __launch_bounds__(256)
void gemm_stream(const float* __restrict__ A, const float* __restrict__ W,
                 const float* __restrict__ bias, float* __restrict__ out) {
    const int N = 256;
    const int t  = threadIdx.x;
    const int n0 = blockIdx.x * 64;
    const int r0 = blockIdx.y * 32;
    const int ty = t >> 4, tx = t & 15;

    const float* Ar0 = A + (r0 + ty * 2 + 0) * K;
    const float* Ar1 = A + (r0 + ty * 2 + 1) * K;
    const float* Wb  = W + n0 + tx * 4;

    float4 bias4 = *(const float4*)(bias + n0 + tx * 4);

    float acc[2][4];
    #pragma unroll
    for (int i = 0; i < 2; i++)
        #pragma unroll
        for (int j = 0; j < 4; j++) acc[i][j] = 0.f;

    // set X = chunk 0
    float4 xA0a = *(const float4*)(Ar0 + 0), xA0b = *(const float4*)(Ar0 + 4);
    float4 xA1a = *(const float4*)(Ar1 + 0), xA1b = *(const float4*)(Ar1 + 4);
    float4 xB[8];
    #pragma unroll
    for (int u = 0; u < 8; u++) xB[u] = *(const float4*)(Wb + u * N);

    float4 yA0a, yA0b, yA1a, yA1b, yB[8];

    #pragma unroll 4
    for (int k0 = 0; k0 < K; k0 += 16) {
        // prefetch chunk k0+8 into set Y, compute set X (k0)
        {
            const int kn = k0 + 8;
            yA0a = *(const float4*)(Ar0 + kn); yA0b = *(const float4*)(Ar0 + kn + 4);
            yA1a = *(const float4*)(Ar1 + kn); yA1b = *(const float4*)(Ar1 + kn + 4);
            #pragma unroll
            for (int u = 0; u < 8; u++) yB[u] = *(const float4*)(Wb + (kn + u) * N);
        }
        GEMM_COMPUTE(xA0, xA1, xB)
        // prefetch chunk k0+16 (clamped) into set X, compute set Y (k0+8)
        {
            int kn = k0 + 16;
            if (kn > K - 8) kn = K - 8;   // harmless reload on last iter
            xA0a = *(const float4*)(Ar0 + kn); xA0b = *(const float4*)(Ar0 + kn + 4);
            xA1a = *(const float4*)(Ar1 + kn); xA1b = *(const float4*)(Ar1 + kn + 4);
            #pragma unroll
            for (int u = 0; u < 8; u++) xB[u] = *(const float4*)(Wb + (kn + u) * N);
        }
        GEMM_COMPUTE(yA0, yA1, yB)
    }

    float bb4[4] = {bias4.x, bias4.y, bias4.z, bias4.w};
    #pragma unroll
    for (int i = 0; i < 2; i++) {
        int row = r0 + ty * 2 + i;
        float4 o;
        float* op = (float*)&o;
        #pragma unroll
        for (int j = 0; j < 4; j++) op[j] = gelu_exact(acc[i][j] + bb4[j]);
        *(float4*)(out + row * N + n0 + tx * 4) = o;
    }
}

// ---------------------------------------------------------------------------
// router (r9-verified): 8 rows/block, grid 512, one col/thread, swizzled Wv.
// ---------------------------------------------------------------------------
__global__ __launch_bounds__(256)
void router_kernel(const float* __restrict__ feats, const float* __restrict__ Wv,
                   const float* __restrict__ bv, const float* __restrict__ centers,
                   float* __restrict__ out, float* __restrict__ vloc_ws) {
    __shared__ float sWv[32 * 272];
    __shared__ float sCent[NC * ND];
    __shared__ float sV[8][ND + 2];
    __shared__ float sScore[8][NC];
    __shared__ float sRout[8][NC];
    const int t = threadIdx.x;
    const int row0 = blockIdx.x * 8;
    {
        #pragma unroll
        for (int q = 0; q < 8; q++) {
            int id = t + q * 256;
            int k = id >> 3, c4 = (id & 7) * 4;
            int kb = k >> 2, kr = k & 3;
            float4 w = ((const float4*)Wv)[id];
            sWv[(c4+0) * 272 + ((kb ^ ((c4+0) & 7)) << 2) + kr] = w.x;
            sWv[(c4+1) * 272 + ((kb ^ ((c4+1) & 7)) << 2) + kr] = w.y;
            sWv[(c4+2) * 272 + ((kb ^ ((c4+2) & 7)) << 2) + kr] = w.z;
            sWv[(c4+3) * 272 + ((kb ^ ((c4+3) & 7)) << 2) + kr] = w.w;
        }
        if (t < 64) ((float4*)sCent)[t] = ((const float4*)centers)[t];
    }
    __syncthreads();
    const int r = t >> 5, cp = t & 31;
    const int row = row0 + r;
    const int cbase = cp * 272, cxor = cp & 7;
    float a0 = bv[cp];
    const float4* f4 = (const float4*)(feats + row * NH);
    for (int k4 = 0; k4 < NH / 4; k4++) {
        float4 f = f4[k4];
        float4 w = *(const float4*)(&sWv[cbase + ((k4 ^ cxor) << 2)]);
        a0 = fmaf(f.x, w.x, a0);
        a0 = fmaf(f.y, w.y, a0);
        a0 = fmaf(f.z, w.z, a0);
        a0 = fmaf(f.w, w.w, a0);
    }
    sV[r][cp] = a0;
    __syncthreads();
    if (t < 64) {
        int rr = t >> 3, c = t & 7;
        float s = 0.f;
        #pragma unroll
        for (int k = 0; k < ND; k++) s = fmaf(sV[rr][k], sCent[c * ND + k], s);
        sScore[rr][c] = s / 5.65685424949238f;
    }
    __syncthreads();
    if (t < 8) {
        const int rr = t, grow = row0 + rr;
        float sc[NC];
        float m = -3.4e38f; int kmax = 0;
        #pragma unroll
        for (int c = 0; c < NC; c++) {
            float s = sScore[rr][c];
            sc[c] = s;
            if (s > m) { m = s; kmax = c; }
        }
        float ssum = 0.f;
        #pragma unroll
        for (int c = 0; c < NC; c++) { float e = expf(sc[c] - m); sc[c] = e; ssum += e; }
        float inv = 1.f / ssum;
        #pragma unroll
        for (int c = 0; c < NC; c++) {
            float rv = sc[c] * inv;
            sRout[rr][c] = rv;
            out[OFF_ROUTER + grow * NC + c] = rv;
        }
        out[OFF_KCHART + grow] = (float)kmax;
    }
    __syncthreads();
    {
        const int col = cp;
        float cb = 0.f;
        #pragma unroll
        for (int c = 0; c < NC; c++) cb = fmaf(sRout[r][c], sCent[c * ND + col], cb);
        float vl = sV[r][col] - cb;
        out[OFF_CBAR + row * ND + col] = cb;
        out[OFF_VLOC + row * ND + col] = vl;
        vloc_ws[row * ND + col] = vl;
    }
}

// ---------------------------------------------------------------------------
// vq_chart v3 (r8/r9-verified): block = 64 rows x 1 chart, grid 512.
// 4 rows/thread argmin, rotated codes, Ws in registers.
// ---------------------------------------------------------------------------
__global__ __launch_bounds__(256, 2)
void vq_chart(const float* __restrict__ codebook, const float* __restrict__ vloc_ws,
              const float* __restrict__ Ws1, const float* __restrict__ bs1,
              const float* __restrict__ Ws2, const float* __restrict__ bs2,
              float* __restrict__ out, float* __restrict__ loss_partial) {
    __shared__ float sCB[NK][36];
    __shared__ float sEn2[NK];
    __shared__ float sV[64][36];
    __shared__ float sBest[16][64];
    __shared__ int   sBidx[16][64];
    __shared__ int   sSel[64];
    __shared__ float sRoutv[64];
    __shared__ float sPscale[64];
    __shared__ float sLossArr[64];
    __shared__ float sWs1T[NHS][36];
    __shared__ float sWs2T[ND][20];
    __shared__ float sbs1[NHS], sbs2v[ND];
    const int t = threadIdx.x;
    const int c = blockIdx.x & 7;
    const int row0 = (blockIdx.x >> 3) * 64;

    {
        const float4* src = (const float4*)(codebook + c * NK * ND);
        #pragma unroll
        for (int q = 0; q < 8; q++) {
            int id = t + q * 256;
            int code = id >> 3, kq = (id & 7) * 4;
            *(float4*)(&sCB[code][kq]) = src[id];
        }
        #pragma unroll
        for (int q = 0; q < 2; q++) {
            int id = t + q * 256;
            int rr = id >> 3, kq = (id & 7) * 4;
            *(float4*)(&sV[rr][kq]) = ((const float4*)(vloc_ws + row0 * ND))[id];
        }
    }
    if (t < 128) {
        float4 w = ((const float4*)Ws1)[t];
        int k = t >> 2, o = (t & 3) * 4;
        sWs1T[o+0][k] = w.x; sWs1T[o+1][k] = w.y;
        sWs1T[o+2][k] = w.z; sWs1T[o+3][k] = w.w;
    } else {
        int u = t - 128;
        float4 w = ((const float4*)Ws2)[u];
        int k = u >> 3, o = (u & 7) * 4;
        sWs2T[o+0][k] = w.x; sWs2T[o+1][k] = w.y;
        sWs2T[o+2][k] = w.z; sWs2T[o+3][k] = w.w;
    }
    if (t < NHS) sbs1[t] = bs1[t];
    else if (t < NHS + ND) sbs2v[t - NHS] = bs2[t - NHS];
    if (t < 64) sRoutv[t] = out[OFF_ROUTER + (row0 + t) * NC + c];
    __syncthreads();
    {
        float s = 0.f;
        #pragma unroll
        for (int q = 0; q < 8; q++) {
            float4 e = *(const float4*)(&sCB[t][q * 4]);
            s = fmaf(e.x, e.x, s); s = fmaf(e.y, e.y, s);
            s = fmaf(e.z, e.z, s); s = fmaf(e.w, e.w, s);
        }
        sEn2[t] = s;
    }
    __syncthreads();

    {
        const int r = t & 15, g = t >> 4;
        float vl[4][ND];
        #pragma unroll
        for (int u = 0; u < 4; u++) {
            #pragma unroll
            for (int q = 0; q < 8; q++) {
                float4 a = *(const float4*)(&sV[r + u * 16][q * 4]);
                vl[u][q*4] = a.x; vl[u][q*4+1] = a.y;
                vl[u][q*4+2] = a.z; vl[u][q*4+3] = a.w;
            }
        }
        float best[4] = {3.4e38f, 3.4e38f, 3.4e38f, 3.4e38f};
        int bi[4] = {0, 0, 0, 0};
        for (int j = 0; j < 16; j++) {
            const int code = g * 16 + ((j + g * 4) & 15);
            float dot[4] = {0.f, 0.f, 0.f, 0.f};
            #pragma unroll
            for (int q = 0; q < 8; q++) {
                float4 e = *(const float4*)(&sCB[code][q * 4]);
                #pragma unroll
                for (int u = 0; u < 4; u++) {
                    dot[u] = fmaf(vl[u][q*4+0], e.x, dot[u]);
                    dot[u] = fmaf(vl[u][q*4+1], e.y, dot[u]);
                    dot[u] = fmaf(vl[u][q*4+2], e.z, dot[u]);
                    dot[u] = fmaf(vl[u][q*4+3], e.w, dot[u]);
                }
            }
            const float en2 = sEn2[code];
            #pragma unroll
            for (int u = 0; u < 4; u++) {
                float d = en2 - 2.f * dot[u];
                if (d < best[u] || (d == best[u] && code < bi[u])) {
                    best[u] = d; bi[u] = code;
                }
            }
        }
        #pragma unroll
        for (int u = 0; u < 4; u++) {
            sBest[g][r + u * 16] = best[u];
            sBidx[g][r + u * 16] = bi[u];
        }
    }
    __syncthreads();
    if (t < 64) {
        float bb = sBest[0][t]; int ii = sBidx[0][t];
        #pragma unroll
        for (int gg = 1; gg < 16; gg++) {
            float v = sBest[gg][t]; int id = sBidx[gg][t];
            if (v < bb || (v == bb && id < ii)) { bb = v; ii = id; }
        }
        sSel[t] = ii;
        out[OFF_IND + (row0 + t) * NC + c] = (float)ii;
        float vn2 = 0.f;
        #pragma unroll
        for (int k = 0; k < ND; k++) { float v = sV[t][k]; vn2 = fmaf(v, v, vn2); }
        float norm = fmaxf(sqrtf(vn2), 1e-6f);
        sPscale[t] = fminf(0.99f / norm, 1.0f);
    }
    __syncthreads();

    const int i = t & 15, r16 = t >> 4;
    const float b1r = sbs1[i];
    const float bo0 = sbs2v[2*i], bo1 = sbs2v[2*i+1];
    float w1c[ND], w2a[NHS], w2b[NHS];
    #pragma unroll
    for (int q = 0; q < 8; q++) {
        float4 w = *(const float4*)(&sWs1T[i][q * 4]);
        w1c[q*4] = w.x; w1c[q*4+1] = w.y; w1c[q*4+2] = w.z; w1c[q*4+3] = w.w;
    }
    #pragma unroll
    for (int q = 0; q < 4; q++) {
        float4 a = *(const float4*)(&sWs2T[2*i][q * 4]);
        w2a[q*4] = a.x; w2a[q*4+1] = a.y; w2a[q*4+2] = a.z; w2a[q*4+3] = a.w;
        float4 b = *(const float4*)(&sWs2T[2*i+1][q * 4]);
        w2b[q*4] = b.x; w2b[q*4+1] = b.y; w2b[q*4+2] = b.z; w2b[q*4+3] = b.w;
    }
    #pragma unroll
    for (int pass = 0; pass < 4; pass++) {
        const int lrow = pass * 16 + r16;
        const int grow = row0 + lrow;
        const int sel = sSel[lrow];
        const float rc = sRoutv[lrow];
        const float ps = sPscale[lrow];
        float dta[ND];
        #pragma unroll
        for (int q = 0; q < 8; q++) {
            float4 vv = *(const float4*)(&sV[lrow][q * 4]);
            float4 ee = *(const float4*)(&sCB[sel][q * 4]);
            dta[q*4+0] = vv.x - ee.x; dta[q*4+1] = vv.y - ee.y;
            dta[q*4+2] = vv.z - ee.z; dta[q*4+3] = vv.w - ee.w;
        }
        float acc1 = b1r;
        #pragma unroll
        for (int k = 0; k < ND; k++) acc1 = fmaf(dta[k], w1c[k], acc1);
        float h = gelu_exact(acc1);
        float a0 = bo0, a1 = bo1;
        #pragma unroll
        for (int k = 0; k < NHS; k++) {
            float s1k = __shfl(h, k, 16);
            a0 = fmaf(s1k, w2a[k], a0);
            a1 = fmaf(s1k, w2b[k], a1);
        }
        out[OFF_ZNALL + (grow * NC + c) * ND + 2*i]     = a0;
        out[OFF_ZNALL + (grow * NC + c) * ND + 2*i + 1] = a1;
        const float e0 = sCB[sel][2*i], e1 = sCB[sel][2*i+1];
        float yp0 = sV[lrow][2*i] * ps, yp1 = sV[lrow][2*i+1] * ps;
        float d0 = e0 - yp0, d1 = e1 - yp1;
        float sq = fmaf(d0, d0, d1 * d1);
        float xn = fmaf(e0, e0, e1 * e1);
        float yn = fmaf(yp0, yp0, yp1 * yp1);
        #pragma unroll
        for (int m = 1; m < 16; m <<= 1) {
            sq += __shfl_xor(sq, m, 16);
            xn += __shfl_xor(xn, m, 16);
            yn += __shfl_xor(yn, m, 16);
        }
        if (i == 0) {
            float denom = fmaxf((1.f - xn) * (1.f - yn), 1e-6f);
            float arg = fmaxf(1.f + 2.f * sq / denom, 1.f + 1e-6f);
            float dd = acoshf(arg);
            sLossArr[lrow] = dd * dd * rc;
        }
    }
    __syncthreads();
    if (t < 64) {
        float v = sLossArr[t];
        #pragma unroll
        for (int off = 32; off > 0; off >>= 1) v += __shfl_down(v, off, 64);
        if (t == 0) loss_partial[blockIdx.x] = v;
    }
}

// ---------------------------------------------------------------------------
// finalize (r9-verified): one col/thread, grid 512 + loss reduce in block 0.
// ---------------------------------------------------------------------------
__global__ __launch_bounds__(256)
void finalize2_kernel(const float* __restrict__ codebook, const float* __restrict__ vloc_ws,
                      float* __restrict__ out, const float* __restrict__ partials) {
    const int gid = blockIdx.x * 256 + threadIdx.x;
    const int row = gid >> 5;
    const int col = gid & 31;
    float rout[NC]; int ind[NC];
    #pragma unroll
    for (int cc = 0; cc < NC; cc++) {
        rout[cc] = out[OFF_ROUTER + row * NC + cc];
        ind[cc]  = (int)out[OFF_IND + row * NC + cc];
    }
    float zn = 0.f, zq = 0.f;
    #pragma unroll
    for (int cc = 0; cc < NC; cc++) {
        const float rcc = rout[cc];
        zn = fmaf(out[OFF_ZNALL + (row * NC + cc) * ND + col], rcc, zn);
        zq = fmaf(codebook[(cc * NK + ind[cc]) * ND + col], rcc, zq);
    }
    const float vl = vloc_ws[row * ND + col];
    const float cb = out[OFF_CBAR + row * ND + col];
    out[OFF_ZN   + row * ND + col] = zn;
    out[OFF_ZTEX + row * ND + col] = vl - zq - zn;
    out[OFF_ZGEO + row * ND + col] = cb + zq + zn;
    if (col == 0) {
        int kc = (int)out[OFF_KCHART + row];
        out[OFF_KCODE + row] = out[OFF_IND + row * NC + kc];
    }
    if (blockIdx.x == 0) {
        __shared__ float sTmp[4];
        const int t = threadIdx.x;
        float v = partials[t] + partials[t + 256];
        #pragma unroll
        for (int off = 32; off > 0; off >>= 1) v += __shfl_down(v, off, 64);
        if ((t & 63) == 0) sTmp[t >> 6] = v;
        __syncthreads();
        if (t == 0) out[OFF_LOSS] = 1.25f * (sTmp[0] + sTmp[1] + sTmp[2] + sTmp[3]) / 4096.f;
    }
}

extern "C" void kernel_launch(void* const* d_in, const int* in_sizes, int n_in,
                              void* d_out, int out_size, void* d_ws, size_t ws_size,
                              hipStream_t stream) {
    const float* x        = (const float*)d_in[0];
    const float* W1       = (const float*)d_in[1];
    const float* b1       = (const float*)d_in[2];
    const float* W2       = (const float*)d_in[3];
    const float* b2       = (const float*)d_in[4];
    const float* Wv       = (const float*)d_in[5];
    const float* bv       = (const float*)d_in[6];
    const float* centers  = (const float*)d_in[7];
    const float* codebook = (const float*)d_in[8];
    const float* Ws1      = (const float*)d_in[9];
    const float* bs1      = (const float*)d_in[10];
    const float* Ws2      = (const float*)d_in[11];
    const float* bs2      = (const float*)d_in[12];
    float* out = (float*)d_out;
    float* ws  = (float*)d_ws;

    float* h1       = ws;                                // 4096*256
    float* feats    = ws + 4096 * 256;                   // 4096*256
    float* vloc     = ws + 2 * 4096 * 256;               // 4096*32
    float* partials = ws + 2 * 4096 * 256 + 4096 * 32;   // 512

    gemm_stream<128><<<dim3(4, 128), dim3(256), 0, stream>>>(x, W1, b1, h1);
    gemm_stream<256><<<dim3(4, 128), dim3(256), 0, stream>>>(h1, W2, b2, feats);
    router_kernel<<<dim3(512), dim3(256), 0, stream>>>(feats, Wv, bv, centers, out, vloc);
    vq_chart<<<dim3(512), dim3(256), 0, stream>>>(codebook, vloc, Ws1, bs1, Ws2, bs2, out, partials);
    finalize2_kernel<<<dim3(512), dim3(256), 0, stream>>>(codebook, vloc, out, partials);
}

// Round 13
// 63.575 us; speedup vs baseline: 3.1540x; 1.9534x over previous
//
#include <hip/hip_runtime.h>
#include <math.h>

#define NB 4096
#define NIN 128
#define NH 256
#define ND 32
#define NC 8
#define NK 256
#define NHS 16

// output offsets (in floats), concatenated in reference return order
#define OFF_KCHART 0
#define OFF_KCODE  4096
#define OFF_ZN     8192
#define OFF_ZTEX   (OFF_ZN + 4096*32)        // 139264
#define OFF_ROUTER (OFF_ZTEX + 4096*32)      // 270336 (float4-aligned)
#define OFF_ZGEO   (OFF_ROUTER + 4096*8)     // 303104
#define OFF_LOSS   (OFF_ZGEO + 4096*32)      // 434176
#define OFF_IND    (OFF_LOSS + 1)            // 434177 (odd -> scalar access only)
#define OFF_ZNALL  (OFF_IND + 4096*8)        // 466945 (odd -> scalar access only)
#define OFF_CBAR   (OFF_ZNALL + 4096*8*32)   // 1515521 (odd -> scalar)
#define OFF_VLOC   (OFF_CBAR + 4096*32)      // 1646593 (odd -> scalar)

__device__ __forceinline__ float gelu_exact(float x) {
    return x * (erff(x / 1.41421356237309504f) + 1.0f) * 0.5f;
}

// ---------------------------------------------------------------------------
// GEMM v5: r6 structure (32x64 tile, 2x4 micro, grid (4,128)=512=2/CU,
// B in LDS dbuf w/ one barrier/tile) with two fixes from r12's diagnosis:
//  - A held in a 4-deep register pipeline indexed by compile-time (c&3):
//    no rotation movs, prefetch distance 4 chunks (~512 cy cover >= L2 lat).
//  - k-tile loop unroll 2 -> LDS buffer parity compile-time.
// FMA order identical to r6/r9 (c,u,j ascending) -> bit-identical output.
// ---------------------------------------------------------------------------
template<int K>
__global__ __launch_bounds__(256)
void gemm_bias_gelu(const float* __restrict__ A, const float* __restrict__ W,
                    const float* __restrict__ bias, float* __restrict__ out) {
    const int N = 256;
    __shared__ float sB[2][32][68];
    const int t  = threadIdx.x;
    const int n0 = blockIdx.x * 64;
    const int r0 = blockIdx.y * 32;
    const int ty = t >> 4, tx = t & 15;
    const int bk = t >> 4, bc = t & 15;

    float4 bias4 = *(const float4*)(bias + n0 + tx * 4);

    float4 pb0 = *(const float4*)(W + bk * N + n0 + bc * 4);
    float4 pb1 = *(const float4*)(W + (bk + 16) * N + n0 + bc * 4);

    const float* Ab0 = A + (r0 + ty * 2 + 0) * K;
    const float* Ab1 = A + (r0 + ty * 2 + 1) * K;

    // 4-deep A pipeline: slot d holds chunk (next to consume + d)
    float4 a0p[4], a1p[4];
    #pragma unroll
    for (int d = 0; d < 4; d++) {
        a0p[d] = *(const float4*)(Ab0 + d * 4);
        a1p[d] = *(const float4*)(Ab1 + d * 4);
    }

    float acc[2][4];
    #pragma unroll
    for (int i = 0; i < 2; i++)
        #pragma unroll
        for (int j = 0; j < 4; j++) acc[i][j] = 0.f;

    int buf = 0;
    #pragma unroll 2
    for (int kk = 0; kk < K; kk += 32) {
        *(float4*)(&sB[buf][bk][bc*4])    = pb0;
        *(float4*)(&sB[buf][bk+16][bc*4]) = pb1;
        __syncthreads();
        if (kk + 32 < K) {
            pb0 = *(const float4*)(W + (kk + 32 + bk) * N + n0 + bc * 4);
            pb1 = *(const float4*)(W + (kk + 32 + bk + 16) * N + n0 + bc * 4);
        }
        #pragma unroll
        for (int c = 0; c < 8; c++) {
            // consume slot c&3 (chunk kk + c*4)
            float4 av0 = a0p[c & 3];
            float4 av1 = a1p[c & 3];
            // refill slot with chunk 4 ahead (clamped; tail loads unused)
            int kpf = kk + (c + 4) * 4;
            if (kpf > K - 4) kpf = K - 4;
            a0p[c & 3] = *(const float4*)(Ab0 + kpf);
            a1p[c & 3] = *(const float4*)(Ab1 + kpf);
            float aa0[4] = {av0.x, av0.y, av0.z, av0.w};
            float aa1[4] = {av1.x, av1.y, av1.z, av1.w};
            #pragma unroll
            for (int u = 0; u < 4; u++) {
                float4 bv = *(const float4*)(&sB[buf][c * 4 + u][tx * 4]);
                float bb[4] = {bv.x, bv.y, bv.z, bv.w};
                #pragma unroll
                for (int j = 0; j < 4; j++) {
                    acc[0][j] = fmaf(aa0[u], bb[j], acc[0][j]);
                    acc[1][j] = fmaf(aa1[u], bb[j], acc[1][j]);
                }
            }
        }
        buf ^= 1;
    }
    float bb4[4] = {bias4.x, bias4.y, bias4.z, bias4.w};
    #pragma unroll
    for (int i = 0; i < 2; i++) {
        int row = r0 + ty * 2 + i;
        float4 o;
        float* op = (float*)&o;
        #pragma unroll
        for (int j = 0; j < 4; j++) op[j] = gelu_exact(acc[i][j] + bb4[j]);
        *(float4*)(out + row * N + n0 + tx * 4) = o;
    }
}

// ---------------------------------------------------------------------------
// router (r9-verified): 8 rows/block, grid 512, one col/thread, swizzled Wv.
// ---------------------------------------------------------------------------
__global__ __launch_bounds__(256)
void router_kernel(const float* __restrict__ feats, const float* __restrict__ Wv,
                   const float* __restrict__ bv, const float* __restrict__ centers,
                   float* __restrict__ out, float* __restrict__ vloc_ws) {
    __shared__ float sWv[32 * 272];
    __shared__ float sCent[NC * ND];
    __shared__ float sV[8][ND + 2];
    __shared__ float sScore[8][NC];
    __shared__ float sRout[8][NC];
    const int t = threadIdx.x;
    const int row0 = blockIdx.x * 8;
    {
        #pragma unroll
        for (int q = 0; q < 8; q++) {
            int id = t + q * 256;
            int k = id >> 3, c4 = (id & 7) * 4;
            int kb = k >> 2, kr = k & 3;
            float4 w = ((const float4*)Wv)[id];
            sWv[(c4+0) * 272 + ((kb ^ ((c4+0) & 7)) << 2) + kr] = w.x;
            sWv[(c4+1) * 272 + ((kb ^ ((c4+1) & 7)) << 2) + kr] = w.y;
            sWv[(c4+2) * 272 + ((kb ^ ((c4+2) & 7)) << 2) + kr] = w.z;
            sWv[(c4+3) * 272 + ((kb ^ ((c4+3) & 7)) << 2) + kr] = w.w;
        }
        if (t < 64) ((float4*)sCent)[t] = ((const float4*)centers)[t];
    }
    __syncthreads();
    const int r = t >> 5, cp = t & 31;
    const int row = row0 + r;
    const int cbase = cp * 272, cxor = cp & 7;
    float a0 = bv[cp];
    const float4* f4 = (const float4*)(feats + row * NH);
    for (int k4 = 0; k4 < NH / 4; k4++) {
        float4 f = f4[k4];
        float4 w = *(const float4*)(&sWv[cbase + ((k4 ^ cxor) << 2)]);
        a0 = fmaf(f.x, w.x, a0);
        a0 = fmaf(f.y, w.y, a0);
        a0 = fmaf(f.z, w.z, a0);
        a0 = fmaf(f.w, w.w, a0);
    }
    sV[r][cp] = a0;
    __syncthreads();
    if (t < 64) {
        int rr = t >> 3, c = t & 7;
        float s = 0.f;
        #pragma unroll
        for (int k = 0; k < ND; k++) s = fmaf(sV[rr][k], sCent[c * ND + k], s);
        sScore[rr][c] = s / 5.65685424949238f;
    }
    __syncthreads();
    if (t < 8) {
        const int rr = t, grow = row0 + rr;
        float sc[NC];
        float m = -3.4e38f; int kmax = 0;
        #pragma unroll
        for (int c = 0; c < NC; c++) {
            float s = sScore[rr][c];
            sc[c] = s;
            if (s > m) { m = s; kmax = c; }
        }
        float ssum = 0.f;
        #pragma unroll
        for (int c = 0; c < NC; c++) { float e = expf(sc[c] - m); sc[c] = e; ssum += e; }
        float inv = 1.f / ssum;
        #pragma unroll
        for (int c = 0; c < NC; c++) {
            float rv = sc[c] * inv;
            sRout[rr][c] = rv;
            out[OFF_ROUTER + grow * NC + c] = rv;
        }
        out[OFF_KCHART + grow] = (float)kmax;
    }
    __syncthreads();
    {
        const int col = cp;
        float cb = 0.f;
        #pragma unroll
        for (int c = 0; c < NC; c++) cb = fmaf(sRout[r][c], sCent[c * ND + col], cb);
        float vl = sV[r][col] - cb;
        out[OFF_CBAR + row * ND + col] = cb;
        out[OFF_VLOC + row * ND + col] = vl;
        vloc_ws[row * ND + col] = vl;
    }
}

// ---------------------------------------------------------------------------
// vq_chart v3 (r8/r9-verified): block = 64 rows x 1 chart, grid 512.
// 4 rows/thread argmin, rotated codes, Ws in registers.
// ---------------------------------------------------------------------------
__global__ __launch_bounds__(256, 2)
void vq_chart(const float* __restrict__ codebook, const float* __restrict__ vloc_ws,
              const float* __restrict__ Ws1, const float* __restrict__ bs1,
              const float* __restrict__ Ws2, const float* __restrict__ bs2,
              float* __restrict__ out, float* __restrict__ loss_partial) {
    __shared__ float sCB[NK][36];
    __shared__ float sEn2[NK];
    __shared__ float sV[64][36];
    __shared__ float sBest[16][64];
    __shared__ int   sBidx[16][64];
    __shared__ int   sSel[64];
    __shared__ float sRoutv[64];
    __shared__ float sPscale[64];
    __shared__ float sLossArr[64];
    __shared__ float sWs1T[NHS][36];
    __shared__ float sWs2T[ND][20];
    __shared__ float sbs1[NHS], sbs2v[ND];
    const int t = threadIdx.x;
    const int c = blockIdx.x & 7;
    const int row0 = (blockIdx.x >> 3) * 64;

    {
        const float4* src = (const float4*)(codebook + c * NK * ND);
        #pragma unroll
        for (int q = 0; q < 8; q++) {
            int id = t + q * 256;
            int code = id >> 3, kq = (id & 7) * 4;
            *(float4*)(&sCB[code][kq]) = src[id];
        }
        #pragma unroll
        for (int q = 0; q < 2; q++) {
            int id = t + q * 256;
            int rr = id >> 3, kq = (id & 7) * 4;
            *(float4*)(&sV[rr][kq]) = ((const float4*)(vloc_ws + row0 * ND))[id];
        }
    }
    if (t < 128) {
        float4 w = ((const float4*)Ws1)[t];
        int k = t >> 2, o = (t & 3) * 4;
        sWs1T[o+0][k] = w.x; sWs1T[o+1][k] = w.y;
        sWs1T[o+2][k] = w.z; sWs1T[o+3][k] = w.w;
    } else {
        int u = t - 128;
        float4 w = ((const float4*)Ws2)[u];
        int k = u >> 3, o = (u & 7) * 4;
        sWs2T[o+0][k] = w.x; sWs2T[o+1][k] = w.y;
        sWs2T[o+2][k] = w.z; sWs2T[o+3][k] = w.w;
    }
    if (t < NHS) sbs1[t] = bs1[t];
    else if (t < NHS + ND) sbs2v[t - NHS] = bs2[t - NHS];
    if (t < 64) sRoutv[t] = out[OFF_ROUTER + (row0 + t) * NC + c];
    __syncthreads();
    {
        float s = 0.f;
        #pragma unroll
        for (int q = 0; q < 8; q++) {
            float4 e = *(const float4*)(&sCB[t][q * 4]);
            s = fmaf(e.x, e.x, s); s = fmaf(e.y, e.y, s);
            s = fmaf(e.z, e.z, s); s = fmaf(e.w, e.w, s);
        }
        sEn2[t] = s;
    }
    __syncthreads();

    {
        const int r = t & 15, g = t >> 4;
        float vl[4][ND];
        #pragma unroll
        for (int u = 0; u < 4; u++) {
            #pragma unroll
            for (int q = 0; q < 8; q++) {
                float4 a = *(const float4*)(&sV[r + u * 16][q * 4]);
                vl[u][q*4] = a.x; vl[u][q*4+1] = a.y;
                vl[u][q*4+2] = a.z; vl[u][q*4+3] = a.w;
            }
        }
        float best[4] = {3.4e38f, 3.4e38f, 3.4e38f, 3.4e38f};
        int bi[4] = {0, 0, 0, 0};
        for (int j = 0; j < 16; j++) {
            const int code = g * 16 + ((j + g * 4) & 15);
            float dot[4] = {0.f, 0.f, 0.f, 0.f};
            #pragma unroll
            for (int q = 0; q < 8; q++) {
                float4 e = *(const float4*)(&sCB[code][q * 4]);
                #pragma unroll
                for (int u = 0; u < 4; u++) {
                    dot[u] = fmaf(vl[u][q*4+0], e.x, dot[u]);
                    dot[u] = fmaf(vl[u][q*4+1], e.y, dot[u]);
                    dot[u] = fmaf(vl[u][q*4+2], e.z, dot[u]);
                    dot[u] = fmaf(vl[u][q*4+3], e.w, dot[u]);
                }
            }
            const float en2 = sEn2[code];
            #pragma unroll
            for (int u = 0; u < 4; u++) {
                float d = en2 - 2.f * dot[u];
                if (d < best[u] || (d == best[u] && code < bi[u])) {
                    best[u] = d; bi[u] = code;
                }
            }
        }
        #pragma unroll
        for (int u = 0; u < 4; u++) {
            sBest[g][r + u * 16] = best[u];
            sBidx[g][r + u * 16] = bi[u];
        }
    }
    __syncthreads();
    if (t < 64) {
        float bb = sBest[0][t]; int ii = sBidx[0][t];
        #pragma unroll
        for (int gg = 1; gg < 16; gg++) {
            float v = sBest[gg][t]; int id = sBidx[gg][t];
            if (v < bb || (v == bb && id < ii)) { bb = v; ii = id; }
        }
        sSel[t] = ii;
        out[OFF_IND + (row0 + t) * NC + c] = (float)ii;
        float vn2 = 0.f;
        #pragma unroll
        for (int k = 0; k < ND; k++) { float v = sV[t][k]; vn2 = fmaf(v, v, vn2); }
        float norm = fmaxf(sqrtf(vn2), 1e-6f);
        sPscale[t] = fminf(0.99f / norm, 1.0f);
    }
    __syncthreads();

    const int i = t & 15, r16 = t >> 4;
    const float b1r = sbs1[i];
    const float bo0 = sbs2v[2*i], bo1 = sbs2v[2*i+1];
    float w1c[ND], w2a[NHS], w2b[NHS];
    #pragma unroll
    for (int q = 0; q < 8; q++) {
        float4 w = *(const float4*)(&sWs1T[i][q * 4]);
        w1c[q*4] = w.x; w1c[q*4+1] = w.y; w1c[q*4+2] = w.z; w1c[q*4+3] = w.w;
    }
    #pragma unroll
    for (int q = 0; q < 4; q++) {
        float4 a = *(const float4*)(&sWs2T[2*i][q * 4]);
        w2a[q*4] = a.x; w2a[q*4+1] = a.y; w2a[q*4+2] = a.z; w2a[q*4+3] = a.w;
        float4 b = *(const float4*)(&sWs2T[2*i+1][q * 4]);
        w2b[q*4] = b.x; w2b[q*4+1] = b.y; w2b[q*4+2] = b.z; w2b[q*4+3] = b.w;
    }
    #pragma unroll
    for (int pass = 0; pass < 4; pass++) {
        const int lrow = pass * 16 + r16;
        const int grow = row0 + lrow;
        const int sel = sSel[lrow];
        const float rc = sRoutv[lrow];
        const float ps = sPscale[lrow];
        float dta[ND];
        #pragma unroll
        for (int q = 0; q < 8; q++) {
            float4 vv = *(const float4*)(&sV[lrow][q * 4]);
            float4 ee = *(const float4*)(&sCB[sel][q * 4]);
            dta[q*4+0] = vv.x - ee.x; dta[q*4+1] = vv.y - ee.y;
            dta[q*4+2] = vv.z - ee.z; dta[q*4+3] = vv.w - ee.w;
        }
        float acc1 = b1r;
        #pragma unroll
        for (int k = 0; k < ND; k++) acc1 = fmaf(dta[k], w1c[k], acc1);
        float h = gelu_exact(acc1);
        float a0 = bo0, a1 = bo1;
        #pragma unroll
        for (int k = 0; k < NHS; k++) {
            float s1k = __shfl(h, k, 16);
            a0 = fmaf(s1k, w2a[k], a0);
            a1 = fmaf(s1k, w2b[k], a1);
        }
        out[OFF_ZNALL + (grow * NC + c) * ND + 2*i]     = a0;
        out[OFF_ZNALL + (grow * NC + c) * ND + 2*i + 1] = a1;
        const float e0 = sCB[sel][2*i], e1 = sCB[sel][2*i+1];
        float yp0 = sV[lrow][2*i] * ps, yp1 = sV[lrow][2*i+1] * ps;
        float d0 = e0 - yp0, d1 = e1 - yp1;
        float sq = fmaf(d0, d0, d1 * d1);
        float xn = fmaf(e0, e0, e1 * e1);
        float yn = fmaf(yp0, yp0, yp1 * yp1);
        #pragma unroll
        for (int m = 1; m < 16; m <<= 1) {
            sq += __shfl_xor(sq, m, 16);
            xn += __shfl_xor(xn, m, 16);
            yn += __shfl_xor(yn, m, 16);
        }
        if (i == 0) {
            float denom = fmaxf((1.f - xn) * (1.f - yn), 1e-6f);
            float arg = fmaxf(1.f + 2.f * sq / denom, 1.f + 1e-6f);
            float dd = acoshf(arg);
            sLossArr[lrow] = dd * dd * rc;
        }
    }
    __syncthreads();
    if (t < 64) {
        float v = sLossArr[t];
        #pragma unroll
        for (int off = 32; off > 0; off >>= 1) v += __shfl_down(v, off, 64);
        if (t == 0) loss_partial[blockIdx.x] = v;
    }
}

// ---------------------------------------------------------------------------
// finalize (r9-verified): one col/thread, grid 512 + loss reduce in block 0.
// ---------------------------------------------------------------------------
__global__ __launch_bounds__(256)
void finalize2_kernel(const float* __restrict__ codebook, const float* __restrict__ vloc_ws,
                      float* __restrict__ out, const float* __restrict__ partials) {
    const int gid = blockIdx.x * 256 + threadIdx.x;
    const int row = gid >> 5;
    const int col = gid & 31;
    float rout[NC]; int ind[NC];
    #pragma unroll
    for (int cc = 0; cc < NC; cc++) {
        rout[cc] = out[OFF_ROUTER + row * NC + cc];
        ind[cc]  = (int)out[OFF_IND + row * NC + cc];
    }
    float zn = 0.f, zq = 0.f;
    #pragma unroll
    for (int cc = 0; cc < NC; cc++) {
        const float rcc = rout[cc];
        zn = fmaf(out[OFF_ZNALL + (row * NC + cc) * ND + col], rcc, zn);
        zq = fmaf(codebook[(cc * NK + ind[cc]) * ND + col], rcc, zq);
    }
    const float vl = vloc_ws[row * ND + col];
    const float cb = out[OFF_CBAR + row * ND + col];
    out[OFF_ZN   + row * ND + col] = zn;
    out[OFF_ZTEX + row * ND + col] = vl - zq - zn;
    out[OFF_ZGEO + row * ND + col] = cb + zq + zn;
    if (col == 0) {
        int kc = (int)out[OFF_KCHART + row];
        out[OFF_KCODE + row] = out[OFF_IND + row * NC + kc];
    }
    if (blockIdx.x == 0) {
        __shared__ float sTmp[4];
        const int t = threadIdx.x;
        float v = partials[t] + partials[t + 256];
        #pragma unroll
        for (int off = 32; off > 0; off >>= 1) v += __shfl_down(v, off, 64);
        if ((t & 63) == 0) sTmp[t >> 6] = v;
        __syncthreads();
        if (t == 0) out[OFF_LOSS] = 1.25f * (sTmp[0] + sTmp[1] + sTmp[2] + sTmp[3]) / 4096.f;
    }
}

extern "C" void kernel_launch(void* const* d_in, const int* in_sizes, int n_in,
                              void* d_out, int out_size, void* d_ws, size_t ws_size,
                              hipStream_t stream) {
    const float* x        = (const float*)d_in[0];
    const float* W1       = (const float*)d_in[1];
    const float* b1       = (const float*)d_in[2];
    const float* W2       = (const float*)d_in[3];
    const float* b2       = (const float*)d_in[4];
    const float* Wv       = (const float*)d_in[5];
    const float* bv       = (const float*)d_in[6];
    const float* centers  = (const float*)d_in[7];
    const float* codebook = (const float*)d_in[8];
    const float* Ws1      = (const float*)d_in[9];
    const float* bs1      = (const float*)d_in[10];
    const float* Ws2      = (const float*)d_in[11];
    const float* bs2      = (const float*)d_in[12];
    float* out = (float*)d_out;
    float* ws  = (float*)d_ws;

    float* h1       = ws;                                // 4096*256
    float* feats    = ws + 4096 * 256;                   // 4096*256
    float* vloc     = ws + 2 * 4096 * 256;               // 4096*32
    float* partials = ws + 2 * 4096 * 256 + 4096 * 32;   // 512

    gemm_bias_gelu<128><<<dim3(4, 128), dim3(256), 0, stream>>>(x, W1, b1, h1);
    gemm_bias_gelu<256><<<dim3(4, 128), dim3(256), 0, stream>>>(h1, W2, b2, feats);
    router_kernel<<<dim3(512), dim3(256), 0, stream>>>(feats, Wv, bv, centers, out, vloc);
    vq_chart<<<dim3(512), dim3(256), 0, stream>>>(codebook, vloc, Ws1, bs1, Ws2, bs2, out, partials);
    finalize2_kernel<<<dim3(512), dim3(256), 0, stream>>>(codebook, vloc, out, partials);
}

// Round 14
// 60.059 us; speedup vs baseline: 3.3387x; 1.0585x over previous
//
#include <hip/hip_runtime.h>
#include <math.h>

#define NB 4096
#define NIN 128
#define NH 256
#define ND 32
#define NC 8
#define NK 256
#define NHS 16

// output offsets (in floats), concatenated in reference return order
#define OFF_KCHART 0
#define OFF_KCODE  4096
#define OFF_ZN     8192
#define OFF_ZTEX   (OFF_ZN + 4096*32)        // 139264
#define OFF_ROUTER (OFF_ZTEX + 4096*32)      // 270336 (float4-aligned)
#define OFF_ZGEO   (OFF_ROUTER + 4096*8)     // 303104
#define OFF_LOSS   (OFF_ZGEO + 4096*32)      // 434176
#define OFF_IND    (OFF_LOSS + 1)            // 434177 (odd -> scalar access only)
#define OFF_ZNALL  (OFF_IND + 4096*8)        // 466945 (odd -> scalar access only)
#define OFF_CBAR   (OFF_ZNALL + 4096*8*32)   // 1515521 (odd -> scalar)
#define OFF_VLOC   (OFF_CBAR + 4096*32)      // 1646593 (odd -> scalar)

__device__ __forceinline__ float gelu_exact(float x) {
    return x * (erff(x / 1.41421356237309504f) + 1.0f) * 0.5f;
}

// ---------------------------------------------------------------------------
// GEMM v6 "W-stationary": out = gelu(A[M][K] @ W[K][256] + b).
// 32x64 tile, 2x4 micro, grid (4,128)=512=2 blocks/CU. The block's ENTIRE
// W-slice [K][64] is staged in LDS once (gemm2: 64 KB, gemm1: 32 KB;
// 2/CU <= 160 KB) -> ONE barrier total, K-loop is barrier-free so waves
// slip freely and loads pipeline across all of K (removes the per-k-tile
// lockstep drain that r12 calibration shows costs ~35 us on the pair).
// A kept in a 4-deep compile-time-indexed register pipeline (r13).
// FMA order (c,u,j ascending, 2 rows interleaved) == r6/r9 -> bit-identical.
// ---------------------------------------------------------------------------
template<int K>
__global__ __launch_bounds__(256)
void gemm_wstat(const float* __restrict__ A, const float* __restrict__ W,
                const float* __restrict__ bias, float* __restrict__ out) {
    __shared__ float sW[K * 64];   // [k][c], row 64 floats (reads are row-local)
    const int t  = threadIdx.x;
    const int n0 = blockIdx.x * 64;
    const int r0 = blockIdx.y * 32;
    const int ty = t >> 4, tx = t & 15;

    // stage W slice once: K*16 float4, K/16 per thread, linear writes
    #pragma unroll
    for (int i = 0; i < K / 16; i++) {
        int id = i * 256 + t;
        int k = id >> 4, c4 = (id & 15) * 4;
        *(float4*)(&sW[k * 64 + c4]) = *(const float4*)(W + k * 256 + n0 + c4);
    }

    float4 bias4 = *(const float4*)(bias + n0 + tx * 4);

    const float* Ab0 = A + (r0 + ty * 2 + 0) * K;
    const float* Ab1 = A + (r0 + ty * 2 + 1) * K;

    // 4-deep A pipeline (slot d = chunk next+d), compile-time slot via c&3
    float4 a0p[4], a1p[4];
    #pragma unroll
    for (int d = 0; d < 4; d++) {
        a0p[d] = *(const float4*)(Ab0 + d * 4);
        a1p[d] = *(const float4*)(Ab1 + d * 4);
    }

    float acc[2][4];
    #pragma unroll
    for (int i = 0; i < 2; i++)
        #pragma unroll
        for (int j = 0; j < 4; j++) acc[i][j] = 0.f;

    __syncthreads();   // the ONLY barrier

    #pragma unroll 4
    for (int c = 0; c < K / 4; c++) {
        float4 av0 = a0p[c & 3];
        float4 av1 = a1p[c & 3];
        int kpf = (c + 4) * 4;
        if (kpf > K - 4) kpf = K - 4;    // clamped tail prefetch (harmless)
        a0p[c & 3] = *(const float4*)(Ab0 + kpf);
        a1p[c & 3] = *(const float4*)(Ab1 + kpf);
        float aa0[4] = {av0.x, av0.y, av0.z, av0.w};
        float aa1[4] = {av1.x, av1.y, av1.z, av1.w};
        #pragma unroll
        for (int u = 0; u < 4; u++) {
            float4 bv = *(const float4*)(&sW[(c * 4 + u) * 64 + tx * 4]);
            float bb[4] = {bv.x, bv.y, bv.z, bv.w};
            #pragma unroll
            for (int j = 0; j < 4; j++) {
                acc[0][j] = fmaf(aa0[u], bb[j], acc[0][j]);
                acc[1][j] = fmaf(aa1[u], bb[j], acc[1][j]);
            }
        }
    }

    float bb4[4] = {bias4.x, bias4.y, bias4.z, bias4.w};
    #pragma unroll
    for (int i = 0; i < 2; i++) {
        int row = r0 + ty * 2 + i;
        float4 o;
        float* op = (float*)&o;
        #pragma unroll
        for (int j = 0; j < 4; j++) op[j] = gelu_exact(acc[i][j] + bb4[j]);
        *(float4*)(out + row * 256 + n0 + tx * 4) = o;
    }
}

// ---------------------------------------------------------------------------
// router (r9-verified): 8 rows/block, grid 512, one col/thread, swizzled Wv.
// ---------------------------------------------------------------------------
__global__ __launch_bounds__(256)
void router_kernel(const float* __restrict__ feats, const float* __restrict__ Wv,
                   const float* __restrict__ bv, const float* __restrict__ centers,
                   float* __restrict__ out, float* __restrict__ vloc_ws) {
    __shared__ float sWv[32 * 272];
    __shared__ float sCent[NC * ND];
    __shared__ float sV[8][ND + 2];
    __shared__ float sScore[8][NC];
    __shared__ float sRout[8][NC];
    const int t = threadIdx.x;
    const int row0 = blockIdx.x * 8;
    {
        #pragma unroll
        for (int q = 0; q < 8; q++) {
            int id = t + q * 256;
            int k = id >> 3, c4 = (id & 7) * 4;
            int kb = k >> 2, kr = k & 3;
            float4 w = ((const float4*)Wv)[id];
            sWv[(c4+0) * 272 + ((kb ^ ((c4+0) & 7)) << 2) + kr] = w.x;
            sWv[(c4+1) * 272 + ((kb ^ ((c4+1) & 7)) << 2) + kr] = w.y;
            sWv[(c4+2) * 272 + ((kb ^ ((c4+2) & 7)) << 2) + kr] = w.z;
            sWv[(c4+3) * 272 + ((kb ^ ((c4+3) & 7)) << 2) + kr] = w.w;
        }
        if (t < 64) ((float4*)sCent)[t] = ((const float4*)centers)[t];
    }
    __syncthreads();
    const int r = t >> 5, cp = t & 31;
    const int row = row0 + r;
    const int cbase = cp * 272, cxor = cp & 7;
    float a0 = bv[cp];
    const float4* f4 = (const float4*)(feats + row * NH);
    for (int k4 = 0; k4 < NH / 4; k4++) {
        float4 f = f4[k4];
        float4 w = *(const float4*)(&sWv[cbase + ((k4 ^ cxor) << 2)]);
        a0 = fmaf(f.x, w.x, a0);
        a0 = fmaf(f.y, w.y, a0);
        a0 = fmaf(f.z, w.z, a0);
        a0 = fmaf(f.w, w.w, a0);
    }
    sV[r][cp] = a0;
    __syncthreads();
    if (t < 64) {
        int rr = t >> 3, c = t & 7;
        float s = 0.f;
        #pragma unroll
        for (int k = 0; k < ND; k++) s = fmaf(sV[rr][k], sCent[c * ND + k], s);
        sScore[rr][c] = s / 5.65685424949238f;
    }
    __syncthreads();
    if (t < 8) {
        const int rr = t, grow = row0 + rr;
        float sc[NC];
        float m = -3.4e38f; int kmax = 0;
        #pragma unroll
        for (int c = 0; c < NC; c++) {
            float s = sScore[rr][c];
            sc[c] = s;
            if (s > m) { m = s; kmax = c; }
        }
        float ssum = 0.f;
        #pragma unroll
        for (int c = 0; c < NC; c++) { float e = expf(sc[c] - m); sc[c] = e; ssum += e; }
        float inv = 1.f / ssum;
        #pragma unroll
        for (int c = 0; c < NC; c++) {
            float rv = sc[c] * inv;
            sRout[rr][c] = rv;
            out[OFF_ROUTER + grow * NC + c] = rv;
        }
        out[OFF_KCHART + grow] = (float)kmax;
    }
    __syncthreads();
    {
        const int col = cp;
        float cb = 0.f;
        #pragma unroll
        for (int c = 0; c < NC; c++) cb = fmaf(sRout[r][c], sCent[c * ND + col], cb);
        float vl = sV[r][col] - cb;
        out[OFF_CBAR + row * ND + col] = cb;
        out[OFF_VLOC + row * ND + col] = vl;
        vloc_ws[row * ND + col] = vl;
    }
}

// ---------------------------------------------------------------------------
// vq_chart v3 (r8/r9-verified): block = 64 rows x 1 chart, grid 512.
// 4 rows/thread argmin, rotated codes, Ws in registers.
// ---------------------------------------------------------------------------
__global__ __launch_bounds__(256, 2)
void vq_chart(const float* __restrict__ codebook, const float* __restrict__ vloc_ws,
              const float* __restrict__ Ws1, const float* __restrict__ bs1,
              const float* __restrict__ Ws2, const float* __restrict__ bs2,
              float* __restrict__ out, float* __restrict__ loss_partial) {
    __shared__ float sCB[NK][36];
    __shared__ float sEn2[NK];
    __shared__ float sV[64][36];
    __shared__ float sBest[16][64];
    __shared__ int   sBidx[16][64];
    __shared__ int   sSel[64];
    __shared__ float sRoutv[64];
    __shared__ float sPscale[64];
    __shared__ float sLossArr[64];
    __shared__ float sWs1T[NHS][36];
    __shared__ float sWs2T[ND][20];
    __shared__ float sbs1[NHS], sbs2v[ND];
    const int t = threadIdx.x;
    const int c = blockIdx.x & 7;
    const int row0 = (blockIdx.x >> 3) * 64;

    {
        const float4* src = (const float4*)(codebook + c * NK * ND);
        #pragma unroll
        for (int q = 0; q < 8; q++) {
            int id = t + q * 256;
            int code = id >> 3, kq = (id & 7) * 4;
            *(float4*)(&sCB[code][kq]) = src[id];
        }
        #pragma unroll
        for (int q = 0; q < 2; q++) {
            int id = t + q * 256;
            int rr = id >> 3, kq = (id & 7) * 4;
            *(float4*)(&sV[rr][kq]) = ((const float4*)(vloc_ws + row0 * ND))[id];
        }
    }
    if (t < 128) {
        float4 w = ((const float4*)Ws1)[t];
        int k = t >> 2, o = (t & 3) * 4;
        sWs1T[o+0][k] = w.x; sWs1T[o+1][k] = w.y;
        sWs1T[o+2][k] = w.z; sWs1T[o+3][k] = w.w;
    } else {
        int u = t - 128;
        float4 w = ((const float4*)Ws2)[u];
        int k = u >> 3, o = (u & 7) * 4;
        sWs2T[o+0][k] = w.x; sWs2T[o+1][k] = w.y;
        sWs2T[o+2][k] = w.z; sWs2T[o+3][k] = w.w;
    }
    if (t < NHS) sbs1[t] = bs1[t];
    else if (t < NHS + ND) sbs2v[t - NHS] = bs2[t - NHS];
    if (t < 64) sRoutv[t] = out[OFF_ROUTER + (row0 + t) * NC + c];
    __syncthreads();
    {
        float s = 0.f;
        #pragma unroll
        for (int q = 0; q < 8; q++) {
            float4 e = *(const float4*)(&sCB[t][q * 4]);
            s = fmaf(e.x, e.x, s); s = fmaf(e.y, e.y, s);
            s = fmaf(e.z, e.z, s); s = fmaf(e.w, e.w, s);
        }
        sEn2[t] = s;
    }
    __syncthreads();

    {
        const int r = t & 15, g = t >> 4;
        float vl[4][ND];
        #pragma unroll
        for (int u = 0; u < 4; u++) {
            #pragma unroll
            for (int q = 0; q < 8; q++) {
                float4 a = *(const float4*)(&sV[r + u * 16][q * 4]);
                vl[u][q*4] = a.x; vl[u][q*4+1] = a.y;
                vl[u][q*4+2] = a.z; vl[u][q*4+3] = a.w;
            }
        }
        float best[4] = {3.4e38f, 3.4e38f, 3.4e38f, 3.4e38f};
        int bi[4] = {0, 0, 0, 0};
        for (int j = 0; j < 16; j++) {
            const int code = g * 16 + ((j + g * 4) & 15);
            float dot[4] = {0.f, 0.f, 0.f, 0.f};
            #pragma unroll
            for (int q = 0; q < 8; q++) {
                float4 e = *(const float4*)(&sCB[code][q * 4]);
                #pragma unroll
                for (int u = 0; u < 4; u++) {
                    dot[u] = fmaf(vl[u][q*4+0], e.x, dot[u]);
                    dot[u] = fmaf(vl[u][q*4+1], e.y, dot[u]);
                    dot[u] = fmaf(vl[u][q*4+2], e.z, dot[u]);
                    dot[u] = fmaf(vl[u][q*4+3], e.w, dot[u]);
                }
            }
            const float en2 = sEn2[code];
            #pragma unroll
            for (int u = 0; u < 4; u++) {
                float d = en2 - 2.f * dot[u];
                if (d < best[u] || (d == best[u] && code < bi[u])) {
                    best[u] = d; bi[u] = code;
                }
            }
        }
        #pragma unroll
        for (int u = 0; u < 4; u++) {
            sBest[g][r + u * 16] = best[u];
            sBidx[g][r + u * 16] = bi[u];
        }
    }
    __syncthreads();
    if (t < 64) {
        float bb = sBest[0][t]; int ii = sBidx[0][t];
        #pragma unroll
        for (int gg = 1; gg < 16; gg++) {
            float v = sBest[gg][t]; int id = sBidx[gg][t];
            if (v < bb || (v == bb && id < ii)) { bb = v; ii = id; }
        }
        sSel[t] = ii;
        out[OFF_IND + (row0 + t) * NC + c] = (float)ii;
        float vn2 = 0.f;
        #pragma unroll
        for (int k = 0; k < ND; k++) { float v = sV[t][k]; vn2 = fmaf(v, v, vn2); }
        float norm = fmaxf(sqrtf(vn2), 1e-6f);
        sPscale[t] = fminf(0.99f / norm, 1.0f);
    }
    __syncthreads();

    const int i = t & 15, r16 = t >> 4;
    const float b1r = sbs1[i];
    const float bo0 = sbs2v[2*i], bo1 = sbs2v[2*i+1];
    float w1c[ND], w2a[NHS], w2b[NHS];
    #pragma unroll
    for (int q = 0; q < 8; q++) {
        float4 w = *(const float4*)(&sWs1T[i][q * 4]);
        w1c[q*4] = w.x; w1c[q*4+1] = w.y; w1c[q*4+2] = w.z; w1c[q*4+3] = w.w;
    }
    #pragma unroll
    for (int q = 0; q < 4; q++) {
        float4 a = *(const float4*)(&sWs2T[2*i][q * 4]);
        w2a[q*4] = a.x; w2a[q*4+1] = a.y; w2a[q*4+2] = a.z; w2a[q*4+3] = a.w;
        float4 b = *(const float4*)(&sWs2T[2*i+1][q * 4]);
        w2b[q*4] = b.x; w2b[q*4+1] = b.y; w2b[q*4+2] = b.z; w2b[q*4+3] = b.w;
    }
    #pragma unroll
    for (int pass = 0; pass < 4; pass++) {
        const int lrow = pass * 16 + r16;
        const int grow = row0 + lrow;
        const int sel = sSel[lrow];
        const float rc = sRoutv[lrow];
        const float ps = sPscale[lrow];
        float dta[ND];
        #pragma unroll
        for (int q = 0; q < 8; q++) {
            float4 vv = *(const float4*)(&sV[lrow][q * 4]);
            float4 ee = *(const float4*)(&sCB[sel][q * 4]);
            dta[q*4+0] = vv.x - ee.x; dta[q*4+1] = vv.y - ee.y;
            dta[q*4+2] = vv.z - ee.z; dta[q*4+3] = vv.w - ee.w;
        }
        float acc1 = b1r;
        #pragma unroll
        for (int k = 0; k < ND; k++) acc1 = fmaf(dta[k], w1c[k], acc1);
        float h = gelu_exact(acc1);
        float a0 = bo0, a1 = bo1;
        #pragma unroll
        for (int k = 0; k < NHS; k++) {
            float s1k = __shfl(h, k, 16);
            a0 = fmaf(s1k, w2a[k], a0);
            a1 = fmaf(s1k, w2b[k], a1);
        }
        out[OFF_ZNALL + (grow * NC + c) * ND + 2*i]     = a0;
        out[OFF_ZNALL + (grow * NC + c) * ND + 2*i + 1] = a1;
        const float e0 = sCB[sel][2*i], e1 = sCB[sel][2*i+1];
        float yp0 = sV[lrow][2*i] * ps, yp1 = sV[lrow][2*i+1] * ps;
        float d0 = e0 - yp0, d1 = e1 - yp1;
        float sq = fmaf(d0, d0, d1 * d1);
        float xn = fmaf(e0, e0, e1 * e1);
        float yn = fmaf(yp0, yp0, yp1 * yp1);
        #pragma unroll
        for (int m = 1; m < 16; m <<= 1) {
            sq += __shfl_xor(sq, m, 16);
            xn += __shfl_xor(xn, m, 16);
            yn += __shfl_xor(yn, m, 16);
        }
        if (i == 0) {
            float denom = fmaxf((1.f - xn) * (1.f - yn), 1e-6f);
            float arg = fmaxf(1.f + 2.f * sq / denom, 1.f + 1e-6f);
            float dd = acoshf(arg);
            sLossArr[lrow] = dd * dd * rc;
        }
    }
    __syncthreads();
    if (t < 64) {
        float v = sLossArr[t];
        #pragma unroll
        for (int off = 32; off > 0; off >>= 1) v += __shfl_down(v, off, 64);
        if (t == 0) loss_partial[blockIdx.x] = v;
    }
}

// ---------------------------------------------------------------------------
// finalize (r9-verified): one col/thread, grid 512 + loss reduce in block 0.
// ---------------------------------------------------------------------------
__global__ __launch_bounds__(256)
void finalize2_kernel(const float* __restrict__ codebook, const float* __restrict__ vloc_ws,
                      float* __restrict__ out, const float* __restrict__ partials) {
    const int gid = blockIdx.x * 256 + threadIdx.x;
    const int row = gid >> 5;
    const int col = gid & 31;
    float rout[NC]; int ind[NC];
    #pragma unroll
    for (int cc = 0; cc < NC; cc++) {
        rout[cc] = out[OFF_ROUTER + row * NC + cc];
        ind[cc]  = (int)out[OFF_IND + row * NC + cc];
    }
    float zn = 0.f, zq = 0.f;
    #pragma unroll
    for (int cc = 0; cc < NC; cc++) {
        const float rcc = rout[cc];
        zn = fmaf(out[OFF_ZNALL + (row * NC + cc) * ND + col], rcc, zn);
        zq = fmaf(codebook[(cc * NK + ind[cc]) * ND + col], rcc, zq);
    }
    const float vl = vloc_ws[row * ND + col];
    const float cb = out[OFF_CBAR + row * ND + col];
    out[OFF_ZN   + row * ND + col] = zn;
    out[OFF_ZTEX + row * ND + col] = vl - zq - zn;
    out[OFF_ZGEO + row * ND + col] = cb + zq + zn;
    if (col == 0) {
        int kc = (int)out[OFF_KCHART + row];
        out[OFF_KCODE + row] = out[OFF_IND + row * NC + kc];
    }
    if (blockIdx.x == 0) {
        __shared__ float sTmp[4];
        const int t = threadIdx.x;
        float v = partials[t] + partials[t + 256];
        #pragma unroll
        for (int off = 32; off > 0; off >>= 1) v += __shfl_down(v, off, 64);
        if ((t & 63) == 0) sTmp[t >> 6] = v;
        __syncthreads();
        if (t == 0) out[OFF_LOSS] = 1.25f * (sTmp[0] + sTmp[1] + sTmp[2] + sTmp[3]) / 4096.f;
    }
}

extern "C" void kernel_launch(void* const* d_in, const int* in_sizes, int n_in,
                              void* d_out, int out_size, void* d_ws, size_t ws_size,
                              hipStream_t stream) {
    const float* x        = (const float*)d_in[0];
    const float* W1       = (const float*)d_in[1];
    const float* b1       = (const float*)d_in[2];
    const float* W2       = (const float*)d_in[3];
    const float* b2       = (const float*)d_in[4];
    const float* Wv       = (const float*)d_in[5];
    const float* bv       = (const float*)d_in[6];
    const float* centers  = (const float*)d_in[7];
    const float* codebook = (const float*)d_in[8];
    const float* Ws1      = (const float*)d_in[9];
    const float* bs1      = (const float*)d_in[10];
    const float* Ws2      = (const float*)d_in[11];
    const float* bs2      = (const float*)d_in[12];
    float* out = (float*)d_out;
    float* ws  = (float*)d_ws;

    float* h1       = ws;                                // 4096*256
    float* feats    = ws + 4096 * 256;                   // 4096*256
    float* vloc     = ws + 2 * 4096 * 256;               // 4096*32
    float* partials = ws + 2 * 4096 * 256 + 4096 * 32;   // 512

    gemm_wstat<128><<<dim3(4, 128), dim3(256), 0, stream>>>(x, W1, b1, h1);
    gemm_wstat<256><<<dim3(4, 128), dim3(256), 0, stream>>>(h1, W2, b2, feats);
    router_kernel<<<dim3(512), dim3(256), 0, stream>>>(feats, Wv, bv, centers, out, vloc);
    vq_chart<<<dim3(512), dim3(256), 0, stream>>>(codebook, vloc, Ws1, bs1, Ws2, bs2, out, partials);
    finalize2_kernel<<<dim3(512), dim3(256), 0, stream>>>(codebook, vloc, out, partials);
}